// Round 1
// 618.054 us; speedup vs baseline: 1.1867x; 1.1867x over previous
//
#include <hip/hip_runtime.h>

#define HIDDEN 4096
#define NH 32
#define NKV 8
#define HD 128
#define LCK 3
#define BB 2
#define SS 1024
#define MTOT (BB * SS)  // 2048

typedef unsigned short u16;
typedef __attribute__((ext_vector_type(8))) short s16x8;   // 8 bf16 (4 VGPRs)
typedef __attribute__((ext_vector_type(4))) float f32x4;

__device__ __forceinline__ u16 f2bf(float f) {  // RNE float->bf16
  unsigned u = __builtin_bit_cast(unsigned, f);
  u += 0x7fffu + ((u >> 16) & 1u);
  return (u16)(u >> 16);
}
__device__ __forceinline__ float bf2f(u16 h) {
  return __builtin_bit_cast(float, (unsigned)h << 16);
}
// async global->LDS, 16B per lane; LDS dest = wave-uniform base + lane*16
__device__ __forceinline__ void gld16(const void* g, void* l) {
  __builtin_amdgcn_global_load_lds((const __attribute__((address_space(1))) void*)g,
                                   (__attribute__((address_space(3))) void*)l, 16, 0, 0);
}

// ---------------------------------------------------------------------------
// fp32 -> bf16 flat convert (hidden_states)
// ---------------------------------------------------------------------------
__global__ __launch_bounds__(256) void convert_h(const float* __restrict__ in,
                                                 u16* __restrict__ out, int n4) {
  int i = blockIdx.x * 256 + threadIdx.x;
  if (i >= n4) return;
  float4 v = ((const float4*)in)[i];
  uint2 o;
  o.x = (unsigned)f2bf(v.x) | ((unsigned)f2bf(v.y) << 16);
  o.y = (unsigned)f2bf(v.z) | ((unsigned)f2bf(v.w) << 16);
  ((uint2*)out)[i] = o;
}

// ---------------------------------------------------------------------------
// W [K][N] fp32  ->  Wt [N][K] bf16   (LDS tile transpose, 64x64)
// ---------------------------------------------------------------------------
__global__ __launch_bounds__(256) void transpose_w(const float* __restrict__ W,
                                                   u16* __restrict__ Wt, int K, int N) {
  __shared__ float tile[64][65];
  const int n0 = blockIdx.x * 64, k0 = blockIdx.y * 64;
  const int ty = threadIdx.x >> 6, tx = threadIdx.x & 63;
#pragma unroll
  for (int i = 0; i < 16; ++i) {
    int r = ty * 16 + i;
    tile[r][tx] = W[(size_t)(k0 + r) * N + n0 + tx];
  }
  __syncthreads();
#pragma unroll
  for (int i = 0; i < 16; ++i) {
    int r = ty * 16 + i;
    Wt[(size_t)(n0 + r) * K + k0 + tx] = f2bf(tile[tx][r]);
  }
}

// ---------------------------------------------------------------------------
// bf16 MFMA GEMM, 256x256 tile / BK=64 / 8 waves (2Mx4N) / 512 threads.
// m201-style 8-phase-per-2-tiles schedule expressed per-tile (4 phases):
//   P1: ds_read B(all 8) + A[f0-3,kk0](4) | stage A-h1(t+1)->buf^1 | 16 MFMA
//   P2: ds_read A[f4-7,kk0]+A[f0-3,kk1](8)| stage B-h0(t+2)->buf   | 16 MFMA
//   P3: ds_read A[f4-7,kk1](4)            | stage B-h1(t+2)->buf   | 16 MFMA
//   P4: (no reads)                        | stage A-h0(t+2)->buf   | 16 MFMA
//        + vmcnt(6) once per tile (3 half-tiles in flight), barrier.
// LDS: 2 buf x (A 32KB + B 32KB) = 128KB, [16x32] subtiles, st_16x32 swizzle
// (col ^= 16 elements when row&8) applied on gld16 SOURCE and ds_read addr.
// C is split into up to 3 column-range destinations (fused QKV).
// ---------------------------------------------------------------------------
template <bool BF16OUT>
__global__ __launch_bounds__(512, 2) void gemm_bt(
    const u16* __restrict__ A, const u16* __restrict__ Bt,
    void* C0v, void* C1v, void* C2v, int N, int K, int n1, int n2) {
  __shared__ __align__(16) char smem[131072];
  const int tid = threadIdx.x, lane = tid & 63, w = tid >> 6;
  const int wr = w >> 2, wc = w & 3;           // wave -> 128x64 C subtile
  const int col16 = lane & 15, quad = lane >> 4;

  // XCD-aware bijective block swizzle (m204): one M-row panel per XCD chunk
  const int nbx = gridDim.x;
  const int nwg = nbx * gridDim.y;
  int fid = blockIdx.y * nbx + blockIdx.x;
  {
    const int q = nwg >> 3, r = nwg & 7;
    const int xcd = fid & 7, lid = fid >> 3;
    fid = (xcd < r ? xcd * (q + 1) : r * (q + 1) + (xcd - r) * q) + lid;
  }
  const int bm = (fid / nbx) << 8, bn = (fid % nbx) << 8;

  // staging: wave w covers subtile (sr = base + (w>>1), sc = w&1); lane l
  // writes row (l>>2), src col pre-swizzled: (l&3)*8 ^ (l&32 ? 16 : 0)
  const int rowlane = lane >> 2;
  const int collane = ((lane & 3) * 8) ^ ((lane & 32) ? 16 : 0);
  const u16* aSrc = A + (size_t)(bm + ((w >> 1) << 4) + rowlane) * K + ((w & 1) << 5) + collane;
  const u16* bSrc = Bt + (size_t)(bn + ((w >> 1) << 4) + rowlane) * K + ((w & 1) << 5) + collane;
  // swizzled ds_read lane offset within a 1KB subtile
  const int laneoff = (lane & 15) * 64 + (((lane >> 4) << 4) ^ ((lane & 8) << 2));
  const int NT = K >> 6;

#define STG(opOfs, src, buf, h, tt)                                              \
  do {                                                                           \
    gld16((src) + (size_t)((h) * 128) * K + (size_t)(tt) * 64,                   \
          smem + (buf) * 65536 + (opOfs) +                                       \
              ((((h) * 8 + (w >> 1)) * 2 + (w & 1)) << 10));                     \
    gld16((src) + (size_t)((h) * 128 + 64) * K + (size_t)(tt) * 64,              \
          smem + (buf) * 65536 + (opOfs) +                                       \
              ((((h) * 8 + 4 + (w >> 1)) * 2 + (w & 1)) << 10));                 \
  } while (0)
#define BARX asm volatile("s_barrier" ::: "memory")
#define LGK0                                                                     \
  do {                                                                           \
    asm volatile("s_waitcnt lgkmcnt(0)" ::: "memory");                           \
    __builtin_amdgcn_sched_barrier(0);                                           \
  } while (0)

  f32x4 acc[8][4];
#pragma unroll
  for (int f = 0; f < 8; ++f)
#pragma unroll
    for (int g = 0; g < 4; ++g) acc[f][g] = (f32x4){0.f, 0.f, 0.f, 0.f};

  // prologue: tile0 {B0,B1,A0,A1}, tile1 {B0,B1,A0}; 14 loads, keep 6 in flight
  STG(32768, bSrc, 0, 0, 0);
  STG(32768, bSrc, 0, 1, 0);
  STG(0, aSrc, 0, 0, 0);
  STG(0, aSrc, 0, 1, 0);
  STG(32768, bSrc, 1, 0, 1);
  STG(32768, bSrc, 1, 1, 1);
  STG(0, aSrc, 1, 0, 1);
  asm volatile("s_waitcnt vmcnt(6)" ::: "memory");
  BARX;

  for (int kt = 0; kt < NT; ++kt) {
    const int buf = kt & 1;
    const char* Af = smem + buf * 65536 + wr * 16384 + laneoff;
    const char* Bf = smem + buf * 65536 + 32768 + wc * 8192 + laneoff;
    s16x8 b0[4], b1[4], a0[4], a1[4];
    // ---- P1: all B + A[f0-3,kk0]; stage A-h1 of tile kt+1 (other buffer) ----
#pragma unroll
    for (int g = 0; g < 4; ++g) {
      b0[g] = *(const s16x8*)(Bf + (g * 2 + 0) * 1024);
      b1[g] = *(const s16x8*)(Bf + (g * 2 + 1) * 1024);
    }
#pragma unroll
    for (int f = 0; f < 4; ++f) a0[f] = *(const s16x8*)(Af + (f * 2 + 0) * 1024);
    if (kt + 1 < NT) STG(0, aSrc, (kt + 1) & 1, 1, kt + 1);
    BARX; LGK0;
    __builtin_amdgcn_s_setprio(1);
#pragma unroll
    for (int f = 0; f < 4; ++f)
#pragma unroll
      for (int g = 0; g < 4; ++g)
        acc[f][g] = __builtin_amdgcn_mfma_f32_16x16x32_bf16(a0[f], b0[g], acc[f][g], 0, 0, 0);
    __builtin_amdgcn_s_setprio(0);
    BARX;
    // ---- P2: A[f4-7,kk0] + A[f0-3,kk1]; stage B-h0 of tile kt+2 ----
#pragma unroll
    for (int f = 0; f < 4; ++f) a1[f] = *(const s16x8*)(Af + ((4 + f) * 2 + 0) * 1024);
#pragma unroll
    for (int f = 0; f < 4; ++f) a0[f] = *(const s16x8*)(Af + (f * 2 + 1) * 1024);
    if (kt + 2 < NT) STG(32768, bSrc, buf, 0, kt + 2);
    BARX; LGK0;
    __builtin_amdgcn_s_setprio(1);
#pragma unroll
    for (int f = 0; f < 4; ++f)
#pragma unroll
      for (int g = 0; g < 4; ++g)
        acc[4 + f][g] = __builtin_amdgcn_mfma_f32_16x16x32_bf16(a1[f], b0[g], acc[4 + f][g], 0, 0, 0);
    __builtin_amdgcn_s_setprio(0);
    BARX;
    // ---- P3: A[f4-7,kk1]; stage B-h1 of tile kt+2 ----
#pragma unroll
    for (int f = 0; f < 4; ++f) a1[f] = *(const s16x8*)(Af + ((4 + f) * 2 + 1) * 1024);
    if (kt + 2 < NT) STG(32768, bSrc, buf, 1, kt + 2);
    BARX; LGK0;
    __builtin_amdgcn_s_setprio(1);
#pragma unroll
    for (int f = 0; f < 4; ++f)
#pragma unroll
      for (int g = 0; g < 4; ++g)
        acc[f][g] = __builtin_amdgcn_mfma_f32_16x16x32_bf16(a0[f], b1[g], acc[f][g], 0, 0, 0);
    __builtin_amdgcn_s_setprio(0);
    BARX;
    // ---- P4: no reads; stage A-h0 of tile kt+2; per-tile counted vmcnt ----
    if (kt + 2 < NT) STG(0, aSrc, buf, 0, kt + 2);
    BARX; LGK0;
    __builtin_amdgcn_s_setprio(1);
#pragma unroll
    for (int f = 0; f < 4; ++f)
#pragma unroll
      for (int g = 0; g < 4; ++g)
        acc[4 + f][g] = __builtin_amdgcn_mfma_f32_16x16x32_bf16(a1[f], b1[g], acc[4 + f][g], 0, 0, 0);
    __builtin_amdgcn_s_setprio(0);
    if (kt < NT - 2) asm volatile("s_waitcnt vmcnt(6)" ::: "memory");
    else if (kt == NT - 2) asm volatile("s_waitcnt vmcnt(0)" ::: "memory");
    BARX;
  }
#undef STG
#undef BARX
#undef LGK0

  // epilogue: pick destination by column tile (wave-uniform)
  float* Cf; u16* Ch; int ldc, nb;
  if (bn < n1)      { ldc = n1;      nb = bn;      Cf = (float*)C0v; Ch = (u16*)C0v; }
  else if (bn < n2) { ldc = n2 - n1; nb = bn - n1; Cf = (float*)C1v; Ch = (u16*)C1v; }
  else              { ldc = N - n2;  nb = bn - n2; Cf = (float*)C2v; Ch = (u16*)C2v; }
#pragma unroll
  for (int f = 0; f < 8; ++f)
#pragma unroll
    for (int g = 0; g < 4; ++g)
#pragma unroll
      for (int r = 0; r < 4; ++r) {
        size_t off = (size_t)(bm + wr * 128 + f * 16 + quad * 4 + r) * ldc +
                     nb + wc * 64 + g * 16 + col16;
        if (BF16OUT) Ch[off] = f2bf(acc[f][g][r]);
        else         Cf[off] = acc[f][g][r];
      }
}

// ---------------------------------------------------------------------------
// RoPE + relayout: Qbf0 [b][s][32][128] -> Qbf [b][h][s][128] (bf16),
//                  K0bf [b][s][8][128]  -> Kbf [b][kvh][s][128]
// ---------------------------------------------------------------------------
__global__ __launch_bounds__(256) void rope_convert(const u16* __restrict__ Qin,
                                                    const u16* __restrict__ Kin,
                                                    u16* __restrict__ Qout,
                                                    u16* __restrict__ Kout) {
  const int per_row = (NH + NKV) * 64;  // 2560
  int idx = blockIdx.x * 256 + threadIdx.x;
  if (idx >= MTOT * per_row) return;
  int row = idx / per_row;          // b*1024 + s
  int rem = idx - row * per_row;
  int hh = rem >> 6, i = rem & 63;
  int s = row & (SS - 1), b = row >> 10;

  float invf = __expf((float)i * (-9.210340371976184f / 64.0f));
  float ang = (float)s * invf;
  float cv = cosf(ang), sv = sinf(ang);

  if (hh < NH) {
    const u16* src = Qin + (size_t)row * (NH * HD) + hh * HD;
    u16* dst = Qout + (((size_t)(b * NH + hh)) * SS + s) * HD;
    float x0 = bf2f(src[i]), x1 = bf2f(src[i + 64]);
    dst[i] = f2bf(x0 * cv - x1 * sv);
    dst[i + 64] = f2bf(x1 * cv + x0 * sv);
  } else {
    int kh = hh - NH;
    const u16* src = Kin + (size_t)row * (NKV * HD) + kh * HD;
    u16* dst = Kout + (((size_t)(b * NKV + kh)) * SS + s) * HD;
    float x0 = bf2f(src[i]), x1 = bf2f(src[i + 64]);
    dst[i] = f2bf(x0 * cv - x1 * sv);
    dst[i + 64] = f2bf(x1 * cv + x0 * sv);
  }
}

// ---------------------------------------------------------------------------
// V0bf [b][s][8][128] -> Vt [b][kvh][d=128][s=1024]  (bf16 tile transpose)
// ---------------------------------------------------------------------------
__global__ __launch_bounds__(256) void transpose_v(const u16* __restrict__ V0,
                                                   u16* __restrict__ Vt) {
  __shared__ u16 tile[64][65];
  const int s0 = blockIdx.x * 64, d0 = blockIdx.y * 64;
  const int bk = blockIdx.z;  // b*8 + kvh
  const int b = bk >> 3, kvh = bk & 7;
  const int ty = threadIdx.x >> 6, tx = threadIdx.x & 63;
#pragma unroll
  for (int i = 0; i < 16; ++i) {
    int r = ty * 16 + i;
    tile[r][tx] = V0[((size_t)(b * SS + s0 + r)) * (NKV * HD) + kvh * HD + d0 + tx];
  }
  __syncthreads();
#pragma unroll
  for (int i = 0; i < 16; ++i) {
    int r = ty * 16 + i;
    Vt[((size_t)bk * HD + d0 + r) * SS + s0 + tx] = tile[tx][r];
  }
}

// ---------------------------------------------------------------------------
// Flash MFMA attention.
// Block = (q-tile of 16, kvh, b); 4 waves = the 4 GQA heads of kvh.
// K-loop over 32-wide KV tiles: QK^T (mfma 16x16x32) -> online softmax in
// C-layout registers (state rows == C rows, no LDS state) -> P to LDS (bf16)
// -> PV (mfma). 3 suffix diagonal blocks folded in via fp32 epilogue.
// Output AObf [b][s][h][d] bf16, rows q>=valid zeroed.
// ---------------------------------------------------------------------------
__global__ __launch_bounds__(256) void attn_mfma(
    const u16* __restrict__ Qbf, const u16* __restrict__ Kbf, const u16* __restrict__ Vt,
    const float* __restrict__ ksuf, const float* __restrict__ vsuf,
    u16* __restrict__ AObf, const int* __restrict__ validp) {
  __shared__ u16 Ksh[16][32][8];    // [d-chunk][k-row][8]  8KB
  __shared__ u16 Vsh[4][128][8];    // [k-chunk][d][8]      8KB
  __shared__ u16 Psh[4][4][16][8];  // [wave][k-chunk][q-row][8] 4KB

  const int qt = 63 - (int)blockIdx.x;  // heavy q-tiles dispatched first
  const int q0 = qt * 16;
  const int kvh = blockIdx.y, b = blockIdx.z;
  const int t = threadIdx.x, lane = t & 63, w = t >> 6;
  const int col = lane & 15, quad = lane >> 4;
  const int h = (kvh << 2) + w;
  const int valid = *validp;

  size_t obase = ((size_t)(b * SS + q0 + quad * 4)) * (NH * HD) + h * HD + col;
  if (q0 >= valid) {
#pragma unroll
    for (int r = 0; r < 4; ++r) {
      size_t o = obase + (size_t)r * (NH * HD);
#pragma unroll
      for (int nt = 0; nt < 8; ++nt) AObf[o + 16 * nt] = 0;
    }
    return;
  }

  const float scale = 0.08838834764831845f;  // 1/sqrt(128)
  // Q fragments (A-operand, loop-invariant): lane holds Q[q0+col][quad*8.. per ds]
  const u16* qptr = Qbf + (((size_t)(b * NH + h)) * SS + q0 + col) * HD;
  s16x8 qf[4];
#pragma unroll
  for (int ds = 0; ds < 4; ++ds) qf[ds] = *(const s16x8*)(qptr + ds * 32 + quad * 8);

  const u16* kbase = Kbf + ((size_t)(b * NKV + kvh)) * SS * HD;
  const u16* vbase = Vt + ((size_t)(b * NKV + kvh)) * HD * SS;

  float m_[4], l_[4];
  f32x4 O_[8];
#pragma unroll
  for (int r = 0; r < 4; ++r) { m_[r] = -1e30f; l_[r] = 0.f; }
#pragma unroll
  for (int nt = 0; nt < 8; ++nt) O_[nt] = (f32x4){0.f, 0.f, 0.f, 0.f};

  const int ntiles = (q0 + 47) >> 5;
  const int o0 = w * 1024 + lane * 16;
  const int o1 = o0 + 4096;

  for (int ti = 0; ti < ntiles; ++ti) {
    const int k0 = ti * 32;
    {  // stage K-tile and V^T-tile via global_load_lds (16B/lane)
      int dc = o0 >> 9, kr = (o0 >> 4) & 31;
      gld16(kbase + (size_t)(k0 + kr) * HD + dc * 8, (char*)Ksh + w * 1024);
      dc = o1 >> 9; kr = (o1 >> 4) & 31;
      gld16(kbase + (size_t)(k0 + kr) * HD + dc * 8, (char*)Ksh + w * 1024 + 4096);
      int kc = o0 >> 11, d = (o0 >> 4) & 127;
      gld16(vbase + (size_t)d * SS + k0 + kc * 8, (char*)Vsh + w * 1024);
      kc = o1 >> 11; d = (o1 >> 4) & 127;
      gld16(vbase + (size_t)d * SS + k0 + kc * 8, (char*)Vsh + w * 1024 + 4096);
    }
    __syncthreads();

    // QK^T: two 16-col subtiles
    f32x4 S0 = (f32x4){0.f,0.f,0.f,0.f}, S1 = (f32x4){0.f,0.f,0.f,0.f};
#pragma unroll
    for (int ds = 0; ds < 4; ++ds) {
      s16x8 kf0 = *(const s16x8*)&Ksh[ds * 4 + quad][col][0];
      s16x8 kf1 = *(const s16x8*)&Ksh[ds * 4 + quad][col + 16][0];
      S0 = __builtin_amdgcn_mfma_f32_16x16x32_bf16(qf[ds], kf0, S0, 0, 0, 0);
      S1 = __builtin_amdgcn_mfma_f32_16x16x32_bf16(qf[ds], kf1, S1, 0, 0, 0);
    }

    // online softmax update (rows = quad*4+r, cols across 16 lanes)
    float al[4], p0v[4], p1v[4];
#pragma unroll
    for (int r = 0; r < 4; ++r) {
      int row_g = q0 + quad * 4 + r;
      float s0 = (k0 + col > row_g) ? -1e30f : S0[r] * scale;
      float s1 = (k0 + 16 + col > row_g) ? -1e30f : S1[r] * scale;
      float tm = fmaxf(s0, s1);
      tm = fmaxf(tm, __shfl_xor(tm, 1));
      tm = fmaxf(tm, __shfl_xor(tm, 2));
      tm = fmaxf(tm, __shfl_xor(tm, 4));
      tm = fmaxf(tm, __shfl_xor(tm, 8));
      float mn = fmaxf(m_[r], tm);
      float a = __expf(m_[r] - mn);
      float p0 = __expf(s0 - mn), p1 = __expf(s1 - mn);
      float rs = p0 + p1;
      rs += __shfl_xor(rs, 1);
      rs += __shfl_xor(rs, 2);
      rs += __shfl_xor(rs, 4);
      rs += __shfl_xor(rs, 8);
      l_[r] = l_[r] * a + rs;
      m_[r] = mn;
      al[r] = a; p0v[r] = p0; p1v[r] = p1;
    }
#pragma unroll
    for (int nt = 0; nt < 8; ++nt)
#pragma unroll
      for (int r = 0; r < 4; ++r) O_[nt][r] *= al[r];

    // P (C-layout) -> LDS in A-operand-friendly chunked layout
    {
      int kcA = col >> 3, kk = col & 7;
#pragma unroll
      for (int r = 0; r < 4; ++r) {
        Psh[w][kcA][quad * 4 + r][kk] = f2bf(p0v[r]);
        Psh[w][2 + kcA][quad * 4 + r][kk] = f2bf(p1v[r]);
      }
    }
    __syncthreads();

    // PV: O[16][128] += P[16][32] @ V[32][128]
    s16x8 pf = *(const s16x8*)&Psh[w][quad][col][0];
#pragma unroll
    for (int nt = 0; nt < 8; ++nt) {
      s16x8 vf = *(const s16x8*)&Vsh[quad][col + 16 * nt][0];
      O_[nt] = __builtin_amdgcn_mfma_f32_16x16x32_bf16(pf, vf, O_[nt], 0, 0, 0);
    }
    __syncthreads();
  }

  // ---- suffix blocks (diagonal kv = q), fp32, folded into online softmax ----
  float sr[3][4];
#pragma unroll
  for (int j = 0; j < 3; ++j) {
    const float* krow = ksuf + ((((size_t)(b * NKV + kvh) * LCK + j)) * SS + q0 + col) * HD;
    float p = 0.f;
#pragma unroll
    for (int ds = 0; ds < 4; ++ds) {
      const float* kp = krow + ds * 32 + quad * 8;
#pragma unroll
      for (int e = 0; e < 8; ++e) p += bf2f((u16)qf[ds][e]) * kp[e];
    }
    p += __shfl_xor(p, 16);
    p += __shfl_xor(p, 32);
    p *= scale;
#pragma unroll
    for (int r = 0; r < 4; ++r) sr[j][r] = __shfl(p, quad * 4 + r);
  }
#pragma unroll
  for (int r = 0; r < 4; ++r) {
    int q = q0 + quad * 4 + r;
    float ms = fmaxf(fmaxf(sr[0][r], sr[1][r]), sr[2][r]);
    float mn = fmaxf(m_[r], ms);
    float a = __expf(m_[r] - mn);
    float p0 = __expf(sr[0][r] - mn);
    float p1 = __expf(sr[1][r] - mn);
    float p2 = __expf(sr[2][r] - mn);
    l_[r] = l_[r] * a + p0 + p1 + p2;
    const float* v0r = vsuf + ((((size_t)(b * NKV + kvh) * LCK + 0)) * SS + q) * HD + col;
    const float* v1r = v0r + (size_t)SS * HD;
    const float* v2r = v1r + (size_t)SS * HD;
#pragma unroll
    for (int nt = 0; nt < 8; ++nt)
      O_[nt][r] = O_[nt][r] * a + p0 * v0r[16 * nt] + p1 * v1r[16 * nt] + p2 * v2r[16 * nt];
    m_[r] = mn;
  }

  // ---- write AObf [b][s][h][d] (bf16); rows >= valid are zero ----
#pragma unroll
  for (int r = 0; r < 4; ++r) {
    int q = q0 + quad * 4 + r;
    size_t o = obase + (size_t)r * (NH * HD);
    if (q >= valid) {
#pragma unroll
      for (int nt = 0; nt < 8; ++nt) AObf[o + 16 * nt] = 0;
    } else {
      float inv = 1.f / l_[r];
#pragma unroll
      for (int nt = 0; nt < 8; ++nt) AObf[o + 16 * nt] = f2bf(O_[nt][r] * inv);
    }
  }
}

// ---------------------------------------------------------------------------
extern "C" void kernel_launch(void* const* d_in, const int* in_sizes, int n_in,
                              void* d_out, int out_size, void* d_ws, size_t ws_size,
                              hipStream_t stream) {
  const float* hidden = (const float*)d_in[0];
  const float* ksuf = (const float*)d_in[1];
  const float* vsuf = (const float*)d_in[2];
  const float* Wq = (const float*)d_in[3];
  const float* Wk = (const float*)d_in[4];
  const float* Wv = (const float*)d_in[5];
  const float* Wo = (const float*)d_in[6];
  const int* validp = (const int*)d_in[7];
  float* out = (float*)d_out;

  // workspace layout (96MB peak, regions aliased across phases)
  char* W = (char*)d_ws;
  u16* Hbf  = (u16*)(W + 0);                     // 16MB  (dead after QKV gemm)
  u16* WqT  = (u16*)(W + ((size_t)16 << 20));    // 32MB  (WqT|WkT|WvT contiguous [6144][4096])
  u16* WkT  = (u16*)(W + ((size_t)48 << 20));    // 8MB
  u16* WvT  = (u16*)(W + ((size_t)56 << 20));    // 8MB
  u16* Qbf0 = (u16*)(W + ((size_t)64 << 20));    // 16MB  (dead after rope)
  u16* K0bf = (u16*)(W + ((size_t)80 << 20));    // 4MB
  u16* V0bf = (u16*)(W + ((size_t)84 << 20));    // 4MB
  u16* Kbf  = (u16*)(W + ((size_t)88 << 20));    // 4MB
  u16* Vt   = (u16*)(W + ((size_t)92 << 20));    // 4MB
  u16* Qbf  = (u16*)(W + 0);                     // alias Hbf
  u16* WoT  = (u16*)(W + ((size_t)16 << 20));    // alias WqT
  u16* AObf = (u16*)(W + ((size_t)64 << 20));    // alias Qbf0

  // 1. convert hidden -> bf16
  convert_h<<<(MTOT * HIDDEN / 4 + 255) / 256, 256, 0, stream>>>(hidden, Hbf, MTOT * HIDDEN / 4);
  // 2. transpose+convert projection weights (B^T for gemm)
  transpose_w<<<dim3(64, 64), 256, 0, stream>>>(Wq, WqT, HIDDEN, NH * HD);
  transpose_w<<<dim3(16, 64), 256, 0, stream>>>(Wk, WkT, HIDDEN, NKV * HD);
  transpose_w<<<dim3(16, 64), 256, 0, stream>>>(Wv, WvT, HIDDEN, NKV * HD);
  // 3. fused QKV projection: N = 4096+1024+1024, bf16 out (256x256 tiles)
  gemm_bt<true><<<dim3(24, 8), 512, 0, stream>>>(
      Hbf, WqT, Qbf0, K0bf, V0bf, 6144, HIDDEN, 4096, 5120);
  // 4. Wo transpose (into dead WqT region)
  transpose_w<<<dim3(64, 64), 256, 0, stream>>>(Wo, WoT, NH * HD, HIDDEN);
  // 5. RoPE + head-major relayout (Qbf over dead Hbf)
  rope_convert<<<(MTOT * (NH + NKV) * 64 + 255) / 256, 256, 0, stream>>>(Qbf0, K0bf, Qbf, Kbf);
  // 6. V transpose to [b][kvh][d][s]
  transpose_v<<<dim3(16, 2, BB * NKV), 256, 0, stream>>>(V0bf, Vt);
  // 7. flash MFMA attention (AObf over dead Qbf0)
  attn_mfma<<<dim3(64, NKV, BB), 256, 0, stream>>>(Qbf, Kbf, Vt, ksuf, vsuf, AObf, validp);
  // 8. output projection (fp32 out, 256x256 tiles)
  gemm_bt<false><<<dim3(16, 8), 512, 0, stream>>>(
      AObf, WoT, out, out, out, HIDDEN, NH * HD, 4096, 4096);
}